// Round 1
// baseline (574.763 us; speedup 1.0000x reference)
//
#include <hip/hip_runtime.h>
#include <hip/hip_bf16.h>

// Problem constants (from reference): nodes [8,4,32,96,96] fp32,
// W_edge [8,32,64] fp32 (Wd = [:, :, :32], Ws = [:, :, 32:]), b_edge [8,32].
// out[i] = sum_{j!=i} relu(Wd_i@x_j + (Ws_i-Wd_i)@x_i + b_i) * x_j + x_i
// applied 3 times. Per-pixel independent across all steps -> single kernel.

#define NN 8        // nodes
#define NSTEPS 3
#define BB 4        // batch
#define CC 32       // channels
#define HH 96
#define WWID 96
#define HWP (HH * WWID)   // 9216 pixels per (node,batch) channel plane
#define TP 32             // pixels per block
#define CP 36             // padded channel stride (16B-aligned, breaks write conflicts)
#define CH 4              // pixels per compute chunk (keeps res[] + code size small)

__global__ __launch_bounds__(256, 2)
void gcn3_kernel(const float* __restrict__ nodes,
                 const float* __restrict__ we,
                 const float* __restrict__ be,
                 float* __restrict__ out) {
    __shared__ float xs[NN * TP * CP];   // 8*32*36*4 = 36864 B

    const int tid = threadIdx.x;
    const int i = tid >> 5;    // receiver node for this thread
    const int o = tid & 31;    // output channel for this thread

    // Per-thread weight rows in registers: wd[d] = Wd_i[o][d], wsd = (Ws-Wd)_i[o][d]
    float wd[CC], wsd[CC];
    const float* wrow = we + (i * CC + o) * (2 * CC);
    #pragma unroll
    for (int d = 0; d < CC; ++d) {
        float a = wrow[d];
        wd[d]  = a;
        wsd[d] = wrow[CC + d] - a;
    }
    const float bias = be[i * CC + o];

    // Pixel tile: TP consecutive hw within one batch (HW=9216 divisible by TP)
    const int q0  = blockIdx.x * TP;
    const int b   = q0 / HWP;
    const int hw0 = q0 - b * HWP;

    // Stage global -> LDS, coalesced (lanes -> consecutive hw)
    #pragma unroll
    for (int k = 0; k < (NN * TP * CC) / 256; ++k) {
        int idx = tid + k * 256;
        int p = idx & (TP - 1);
        int c = (idx >> 5) & (CC - 1);
        int n = idx >> 10;
        xs[(n * TP + p) * CP + c] =
            nodes[(size_t)(n * BB + b) * (CC * HWP) + (size_t)c * HWP + hw0 + p];
    }
    __syncthreads();

    #pragma unroll 1
    for (int step = 0; step < NSTEPS; ++step) {
        #pragma unroll 1
        for (int pc = 0; pc < TP; pc += CH) {
            float res[CH];
            #pragma unroll
            for (int pp = 0; pp < CH; ++pp) {
                const int p = pc + pp;
                const float* xi = &xs[(i * TP + p) * CP];
                // Q = (Ws-Wd)_i @ x_i + b   (two accumulation chains for ILP)
                float qa = bias, qb = 0.f;
                #pragma unroll
                for (int d4 = 0; d4 < CC / 4; ++d4) {
                    float4 xv = ((const float4*)xi)[d4];
                    qa = fmaf(wsd[4 * d4 + 0], xv.x, qa);
                    qb = fmaf(wsd[4 * d4 + 1], xv.y, qb);
                    qa = fmaf(wsd[4 * d4 + 2], xv.z, qa);
                    qb = fmaf(wsd[4 * d4 + 3], xv.w, qb);
                }
                const float q = qa + qb;
                float acc = xi[o];   // + nodes[i] residual
                #pragma unroll
                for (int j = 0; j < NN; ++j) {
                    const float* xj = &xs[(j * TP + p) * CP];
                    float ya = q, yb = 0.f;
                    #pragma unroll
                    for (int d4 = 0; d4 < CC / 4; ++d4) {
                        float4 xv = ((const float4*)xj)[d4];
                        ya = fmaf(wd[4 * d4 + 0], xv.x, ya);
                        yb = fmaf(wd[4 * d4 + 1], xv.y, yb);
                        ya = fmaf(wd[4 * d4 + 2], xv.z, ya);
                        yb = fmaf(wd[4 * d4 + 3], xv.w, yb);
                    }
                    float g = fmaxf(ya + yb, 0.f);
                    g = (j == i) ? 0.f : g;       // mask diagonal (after relu, matches ref)
                    acc = fmaf(g, xj[o], acc);
                }
                res[pp] = acc;
            }
            // All waves have finished reading this chunk's pixels before overwrite.
            __syncthreads();
            #pragma unroll
            for (int pp = 0; pp < CH; ++pp)
                xs[(i * TP + pc + pp) * CP + o] = res[pp];
        }
        __syncthreads();   // chunk writes visible before next step's reads
    }

    // LDS -> global, coalesced
    #pragma unroll
    for (int k = 0; k < (NN * TP * CC) / 256; ++k) {
        int idx = tid + k * 256;
        int p = idx & (TP - 1);
        int c = (idx >> 5) & (CC - 1);
        int n = idx >> 10;
        out[(size_t)(n * BB + b) * (CC * HWP) + (size_t)c * HWP + hw0 + p] =
            xs[(n * TP + p) * CP + c];
    }
}

extern "C" void kernel_launch(void* const* d_in, const int* in_sizes, int n_in,
                              void* d_out, int out_size, void* d_ws, size_t ws_size,
                              hipStream_t stream) {
    const float* nodes  = (const float*)d_in[0];
    const float* W_edge = (const float*)d_in[1];
    const float* b_edge = (const float*)d_in[2];
    float* out = (float*)d_out;

    const int n_pixels = BB * HWP;            // 36864
    dim3 grid(n_pixels / TP);                 // 1152 blocks
    dim3 block(256);
    gcn3_kernel<<<grid, block, 0, stream>>>(nodes, W_edge, b_edge, out);
}

// Round 2
// 160.875 us; speedup vs baseline: 3.5727x; 3.5727x over previous
//
#include <hip/hip_runtime.h>
#include <hip/hip_bf16.h>

// out[i] = sum_{j!=i} relu(Wd_i@x_j + (Ws_i-Wd_i)@x_i + b_i) * x_j + x_i, 3 steps.
// MFMA 16x16x32 bf16 with 3-way bf16 splitting (hi/mid/lo) of W and x for
// fp32-equivalent accuracy (6 product terms kept, dropped terms ~2^-27).
// Block: 256 thr = 4 waves; wave w handles receivers w and w+4; 16 pixels/block.
// LDS: fp32 master copy (gating/residual) + 3 bf16 split copies (MFMA B-frags).

#define NN 8
#define NSTEPS 3
#define BB 4
#define CC 32
#define HWSZ 9216
#define PX 16
#define CPF 36   // xf channel stride (floats): 2-way bank conflict only
#define CPS 40   // xs channel stride (bf16): 2-way bank conflict only

typedef __bf16 bf16x8 __attribute__((ext_vector_type(8)));
typedef __bf16 bf16x4 __attribute__((ext_vector_type(4)));
typedef float f32x4 __attribute__((ext_vector_type(4)));

#define MFMA(A, B, C) __builtin_amdgcn_mfma_f32_16x16x32_bf16((A), (B), (C), 0, 0, 0)

__device__ __forceinline__ void split3(float v, __bf16& h, __bf16& m, __bf16& l) {
    h = (__bf16)v;
    float r1 = v - (float)h;
    m = (__bf16)r1;
    l = (__bf16)(r1 - (float)m);
}

__global__ __launch_bounds__(256, 2)
void gcn3_mfma(const float* __restrict__ nodes,
               const float* __restrict__ we,
               const float* __restrict__ be,
               float* __restrict__ out) {
    __shared__ float  xf[NN][PX][CPF];        // 18432 B fp32 master
    __shared__ __bf16 xs[3][NN][PX][CPS];     // 30720 B bf16 splits

    const int tid  = threadIdx.x;
    const int wid  = tid >> 6;
    const int lane = tid & 63;
    const int col  = lane & 15;    // px within tile (B/C "n"), row m for A
    const int quad = lane >> 4;    // 0..3

    const int irec[2] = { wid, wid + 4 };

    // ---- A-fragments: Wd and Wsd=(Ws-Wd), 3-way split, 2 M-tiles, 2 receivers ----
    // A[m=col][k=quad*8+t] per tile; weight row o = 16*tile + col.
    bf16x8 awd[2][2][3];   // [rec][tile][split]
    bf16x8 awsd[2][2][3];
    f32x4  bias[2][2];
    #pragma unroll
    for (int r = 0; r < 2; ++r) {
        #pragma unroll
        for (int t = 0; t < 2; ++t) {
            const float* wp = we + (size_t)(irec[r] * CC + 16 * t + col) * (2 * CC) + quad * 8;
            f32x4 wd0 = *(const f32x4*)(wp);
            f32x4 wd1 = *(const f32x4*)(wp + 4);
            f32x4 ws0 = *(const f32x4*)(wp + CC);
            f32x4 ws1 = *(const f32x4*)(wp + CC + 4);
            #pragma unroll
            for (int k = 0; k < 8; ++k) {
                float d = (k < 4) ? wd0[k & 3] : wd1[k & 3];
                float s = (k < 4) ? ws0[k & 3] : ws1[k & 3];
                __bf16 h, m, l;
                split3(d, h, m, l);
                awd[r][t][0][k] = h; awd[r][t][1][k] = m; awd[r][t][2][k] = l;
                split3(s - d, h, m, l);
                awsd[r][t][0][k] = h; awsd[r][t][1][k] = m; awsd[r][t][2][k] = l;
            }
            #pragma unroll
            for (int k = 0; k < 4; ++k)
                bias[r][t][k] = be[irec[r] * CC + 16 * t + quad * 4 + k];
        }
    }

    // ---- stage 16 px * 8 nodes * 32 ch into LDS (fp32 + 3 splits) ----
    const int q0  = blockIdx.x * PX;
    const int b   = q0 / HWSZ;
    const int hw0 = q0 - b * HWSZ;

    #pragma unroll
    for (int kk = 0; kk < 4; ++kk) {
        int idx = tid + kk * 256;          // over 1024 float4s
        int p4  = (idx & 3) * 4;
        int c   = (idx >> 2) & 31;
        int n   = idx >> 7;
        f32x4 v = *(const f32x4*)(nodes + (size_t)((n * BB + b) * CC + c) * HWSZ + hw0 + p4);
        #pragma unroll
        for (int e = 0; e < 4; ++e) {
            float x = v[e];
            xf[n][p4 + e][c] = x;
            __bf16 h, m, l;
            split3(x, h, m, l);
            xs[0][n][p4 + e][c] = h;
            xs[1][n][p4 + e][c] = m;
            xs[2][n][p4 + e][c] = l;
        }
    }
    __syncthreads();

    #pragma unroll 1
    for (int step = 0; step < NSTEPS; ++step) {
        // --- Q = Wsd_i @ x_i + b (6 split-products, C seeded with bias) ---
        f32x4 qf[2][2];
        #pragma unroll
        for (int r = 0; r < 2; ++r) {
            bf16x8 bq[3];
            #pragma unroll
            for (int s = 0; s < 3; ++s)
                bq[s] = *(const bf16x8*)&xs[s][irec[r]][col][quad * 8];
            #pragma unroll
            for (int t = 0; t < 2; ++t) {
                f32x4 acc = bias[r][t];
                acc = MFMA(awsd[r][t][0], bq[0], acc);
                acc = MFMA(awsd[r][t][0], bq[1], acc);
                acc = MFMA(awsd[r][t][1], bq[0], acc);
                acc = MFMA(awsd[r][t][0], bq[2], acc);
                acc = MFMA(awsd[r][t][2], bq[0], acc);
                acc = MFMA(awsd[r][t][1], bq[1], acc);
                qf[r][t] = acc;
            }
        }
        // --- msg accumulators seeded with residual x_i (C-layout fp32 read) ---
        f32x4 msg[2][2];
        #pragma unroll
        for (int r = 0; r < 2; ++r)
            #pragma unroll
            for (int t = 0; t < 2; ++t)
                msg[r][t] = *(const f32x4*)&xf[irec[r]][col][16 * t + quad * 4];

        // --- sender loop: E = Wd_i @ x_j + Q; msg += relu(E) * x_j ---
        #pragma unroll
        for (int j = 0; j < NN; ++j) {
            bf16x8 bj[3];
            #pragma unroll
            for (int s = 0; s < 3; ++s)
                bj[s] = *(const bf16x8*)&xs[s][j][col][quad * 8];
            f32x4 xg[2];
            #pragma unroll
            for (int t = 0; t < 2; ++t)
                xg[t] = *(const f32x4*)&xf[j][col][16 * t + quad * 4];
            #pragma unroll
            for (int r = 0; r < 2; ++r) {
                const bool diag = (j == irec[r]);
                #pragma unroll
                for (int t = 0; t < 2; ++t) {
                    f32x4 e = qf[r][t];
                    e = MFMA(awd[r][t][0], bj[0], e);
                    e = MFMA(awd[r][t][0], bj[1], e);
                    e = MFMA(awd[r][t][1], bj[0], e);
                    e = MFMA(awd[r][t][0], bj[2], e);
                    e = MFMA(awd[r][t][2], bj[0], e);
                    e = MFMA(awd[r][t][1], bj[1], e);
                    #pragma unroll
                    for (int k = 0; k < 4; ++k) {
                        float g = diag ? 0.0f : fmaxf(e[k], 0.0f);
                        msg[r][t][k] = fmaf(g, xg[t][k], msg[r][t][k]);
                    }
                }
            }
        }
        __syncthreads();   // all reads of old x done
        // --- write back new x_i (fp32 master + re-split bf16 copies) ---
        #pragma unroll
        for (int r = 0; r < 2; ++r) {
            #pragma unroll
            for (int t = 0; t < 2; ++t) {
                *(f32x4*)&xf[irec[r]][col][16 * t + quad * 4] = msg[r][t];
                bf16x4 h4, m4, l4;
                #pragma unroll
                for (int k = 0; k < 4; ++k) {
                    __bf16 h, m, l;
                    split3(msg[r][t][k], h, m, l);
                    h4[k] = h; m4[k] = m; l4[k] = l;
                }
                *(bf16x4*)&xs[0][irec[r]][col][16 * t + quad * 4] = h4;
                *(bf16x4*)&xs[1][irec[r]][col][16 * t + quad * 4] = m4;
                *(bf16x4*)&xs[2][irec[r]][col][16 * t + quad * 4] = l4;
            }
        }
        __syncthreads();   // new x visible before next step
    }

    // ---- LDS -> global ----
    #pragma unroll
    for (int kk = 0; kk < 4; ++kk) {
        int idx = tid + kk * 256;
        int p4  = (idx & 3) * 4;
        int c   = (idx >> 2) & 31;
        int n   = idx >> 7;
        f32x4 v;
        #pragma unroll
        for (int e = 0; e < 4; ++e) v[e] = xf[n][p4 + e][c];
        *(f32x4*)(out + (size_t)((n * BB + b) * CC + c) * HWSZ + hw0 + p4) = v;
    }
}

extern "C" void kernel_launch(void* const* d_in, const int* in_sizes, int n_in,
                              void* d_out, int out_size, void* d_ws, size_t ws_size,
                              hipStream_t stream) {
    const float* nodes  = (const float*)d_in[0];
    const float* W_edge = (const float*)d_in[1];
    const float* b_edge = (const float*)d_in[2];
    float* outp = (float*)d_out;

    dim3 grid((BB * HWSZ) / PX);   // 2304
    dim3 block(256);
    gcn3_mfma<<<grid, block, 0, stream>>>(nodes, W_edge, b_edge, outp);
}